// Round 12
// baseline (263.620 us; speedup 1.0000x reference)
//
#include <hip/hip_runtime.h>

// RNN: B=2048 chains, T=1024 steps, H=64, I=1. One wave per chain,
// 2048 blocks (2 waves/SIMD TLP).
//
// Round-12: r11 + one-level XOR reduction tree with early exchanges.
// O(pi) = m0(l) + m1(l^16) + m2(l^32) + m3(l^48)  (verified algebra), so
//   t = (m0 + swz16(m1)) + (shfl^32(m2) + shfl^48(m3))
// -- one exchange level instead of two serialized ones. m3/m2 chains are
// computed FIRST so their DS-pipe exchanges issue early and hide under
// m1/m0's remaining 16 fdot2s. Each slot = 2 chains of depth 4.
//
// Layout (r9/r11-verified): lane (a=lane>>4, bq=lane&15) holds h[4bq+a].
// Slot s accumulates output 4bq+(s^a). row_ror:2j sources lane (bq-2j)&15.

constexpr int T_STEPS = 1024;
constexpr int H = 64;

typedef float v4f __attribute__((ext_vector_type(4)));
typedef _Float16 h2 __attribute__((ext_vector_type(2)));

template <int CTRL>
__device__ __forceinline__ h2 dpp_movh2(h2 x) {
    return __builtin_bit_cast(h2,
        __builtin_amdgcn_mov_dpp(__builtin_bit_cast(int, x), CTRL, 0xF, 0xF, true));
}
template <int CTRL>
__device__ __forceinline__ float dpp_movf(float x) {
    return __builtin_bit_cast(float,
        __builtin_amdgcn_mov_dpp(__builtin_bit_cast(int, x), CTRL, 0xF, 0xF, true));
}

__device__ __forceinline__ float swz16(float x) {
    // ds_swizzle xor lane^16 within 32-lane halves (BitMode 0x401F).
    return __builtin_bit_cast(float,
        __builtin_amdgcn_ds_swizzle(__builtin_bit_cast(int, x), 0x401F));
}

__device__ __forceinline__ float tanh_fast(float s) {
    // tanh(s) = 1 - 2/(exp2(s*2log2e)+1); saturates correctly at +-1.
    const float e = __builtin_amdgcn_exp2f(s * 2.88539008177792681472f);
    return 1.f - 2.f * __builtin_amdgcn_rcpf(e + 1.f);
}

__global__
__attribute__((amdgpu_flat_work_group_size(64, 64), amdgpu_waves_per_eu(2, 2)))
void rnn_fused(
    const float* __restrict__ x,      // [B, T, 1]
    const float* __restrict__ W_ih,   // [H, 1]
    const float* __restrict__ W_hh,   // [H, H] row-major
    const float* __restrict__ b_ih,   // [H]
    const float* __restrict__ b_hh,   // [H]
    const float* __restrict__ W_out,  // [1, H]
    const float* __restrict__ b_out,  // [1]
    float* __restrict__ out)          // [B, 1]
{
    const int bidx = blockIdx.x;
    const int lane = threadIdx.x;     // 0..63
    const int a    = lane >> 4;       // k-residue class / row
    const int bq   = lane & 15;       // position within row
    const int pi   = 4 * bq + a;      // my output index (resident h index)

    __shared__ v4f xs4[T_STEPS / 4];  // 4 KiB: x[bidx, :]

    // Stage x[bidx, :], coalesced float4.
    const v4f* xrow = reinterpret_cast<const v4f*>(x + (size_t)bidx * T_STEPS);
    #pragma unroll
    for (int k = 0; k < T_STEPS / 4 / 64; ++k)
        xs4[lane + 64 * k] = xrow[lane + 64 * k];

    // W as packed f16 pairs. Slot s = output o_s = 4bq+(s^a); rotation j
    // sees the h-pair of row-lane c=(bq-2j)&15: ( h[4c+a], h[4(c^1)+a] ).
    h2 w2[4][8];
    #pragma unroll
    for (int s = 0; s < 4; ++s) {
        const int o = 4 * bq + (s ^ a);
        const float* wr = W_hh + (size_t)o * H;
        #pragma unroll
        for (int j = 0; j < 8; ++j) {
            const int c = (bq - 2 * j) & 15;
            w2[s][j] = h2{(_Float16)wr[4 * c + a], (_Float16)wr[4 * (c ^ 1) + a]};
        }
    }
    #pragma unroll
    for (int s = 0; s < 4; ++s)
        #pragma unroll
        for (int j = 0; j < 8; ++j)
            asm volatile("" : "+v"(w2[s][j]));   // keep in arch VGPRs

    // Per-lane scalars for output pi (fp32 path).
    const float wihp  = W_ih[pi];
    const float biasp = b_ih[pi] + b_hh[pi];
    const float woutp = W_out[pi];

    float hn = 0.f;                   // resident h[pi] in fp32; h0 = 0

    auto step = [&](float xv) {
        const float seed = fmaf(xv, wihp, biasp);
        // pack (own, ^1-partner) as f16x2, then 7 packed rotations.
        const float hp = dpp_movf<0xB1>(hn);          // quad_perm [1,0,3,2]
        const h2 p0 = __builtin_bit_cast(h2, __builtin_amdgcn_cvt_pkrtz(hn, hp));
        const h2 q1 = dpp_movh2<0x122>(p0);           // row_ror:2
        const h2 q2 = dpp_movh2<0x124>(p0);           // row_ror:4
        const h2 q3 = dpp_movh2<0x126>(p0);           // row_ror:6
        const h2 q4 = dpp_movh2<0x128>(p0);           // row_ror:8
        const h2 q5 = dpp_movh2<0x12A>(p0);           // row_ror:10
        const h2 q6 = dpp_movh2<0x12C>(p0);           // row_ror:12
        const h2 q7 = dpp_movh2<0x12E>(p0);           // row_ror:14

        // Slot dot: two chains of depth 4 (C0 seeds chain a).
        #define DOT8(S, C0)                                                  \
            ({ float _a = __builtin_amdgcn_fdot2(p0, w2[S][0], (C0), false); \
               _a = __builtin_amdgcn_fdot2(q1, w2[S][1], _a, false);         \
               _a = __builtin_amdgcn_fdot2(q2, w2[S][2], _a, false);         \
               _a = __builtin_amdgcn_fdot2(q3, w2[S][3], _a, false);         \
               float _b = __builtin_amdgcn_fdot2(q4, w2[S][4], 0.f, false);  \
               _b = __builtin_amdgcn_fdot2(q5, w2[S][5], _b, false);         \
               _b = __builtin_amdgcn_fdot2(q6, w2[S][6], _b, false);         \
               _b = __builtin_amdgcn_fdot2(q7, w2[S][7], _b, false);         \
               _a + _b; })

        // m3/m2 first: their cross-lane exchanges issue early and hide
        // under m1/m0's 16 remaining fdot2s.
        const float m3 = DOT8(3, 0.f);
        const float m2 = DOT8(2, 0.f);
        const float e3 = __shfl_xor(m3, 48);          // from lane^48
        const float e2 = __shfl_xor(m2, 32);          // from lane^32
        const float m1 = DOT8(1, 0.f);
        const float m0 = DOT8(0, seed);
        const float e1 = swz16(m1);                   // from lane^16
        #undef DOT8

        const float t = (m0 + e1) + (e2 + e3);        // one-level tree
        hn = tanh_fast(t);            // = h_new[pi], fp32, at its home lane
    };

    #pragma unroll 1
    for (int t4 = 0; t4 < T_STEPS / 4; ++t4) {
        const v4f xq = xs4[t4];       // uniform ds_read_b128
        step(xq.x);
        step(xq.y);
        step(xq.z);
        step(xq.w);
    }

    // out = sigmoid(sum_i h[i] * W_out[i] + b_out); pi is a bijection of
    // lanes, so a full-wave sum covers all 64 outputs. fp32 throughout.
    float p = hn * woutp;
    #pragma unroll
    for (int off = 1; off <= 32; off <<= 1)
        p += __shfl_xor(p, off);
    if (lane == 0)
        out[bidx] = 1.f / (1.f + __expf(-(p + b_out[0])));
}

extern "C" void kernel_launch(void* const* d_in, const int* in_sizes, int n_in,
                              void* d_out, int out_size, void* d_ws, size_t ws_size,
                              hipStream_t stream)
{
    const float* x     = (const float*)d_in[0];
    const float* W_ih  = (const float*)d_in[1];
    const float* W_hh  = (const float*)d_in[2];
    const float* b_ih  = (const float*)d_in[3];
    const float* b_hh  = (const float*)d_in[4];
    const float* W_out = (const float*)d_in[5];
    const float* b_out = (const float*)d_in[6];
    float* out = (float*)d_out;

    const int B = out_size;           // one wave per chain
    rnn_fused<<<B, 64, 0, stream>>>(x, W_ih, W_hh, b_ih, b_hh, W_out, b_out, out);
}